// Round 18
// baseline (23.157 us; speedup 1.0000x reference)
//
#include <hip/hip_runtime.h>

#define INDIM  128
#define OUTDIM 128
#define GSZ    5
#define BATCH  1024
#define KC     144       // K-chunks: 128 basis (kc=in) + 16 silu chunks

typedef _Float16 half_t;
typedef _Float16 half8 __attribute__((ext_vector_type(8)));
typedef float    f32x4 __attribute__((ext_vector_type(4)));

// ws layout (half_t units), all K-chunk-major:
//  Bh2ex [144][1024][8] : [kc][b][j]  kc<128: basis_j(b, in=kc)
//                                     kc>=128: silu(b, in=(kc-128)*8+j)
//  Wc2   [144][128][8]  : [kc][o][j]  kc<128: csp*W[o,in=kc,j]
//                                     kc>=128: cre[o, in=(kc-128)*8+j]
#define WC2_OFF  (KC * BATCH * 8)                  // 1179648

// 8 weight-slot basis values for one x (uniform cubic B-spline, reference knots)
__device__ __forceinline__ half8 basis8(float x, float g0, float g5) {
    const float h  = (g5 - g0) * (1.0f / GSZ);
    const float e0 = ((g0 - h) - h) - h;       // matches reference sequential knot build
    const float xb = (x - e0) * (1.0f / h);
    const float jf = floorf(xb);
    const int   j0 = (int)jf;
    const float u  = xb - jf;
    const float t1 = 1.0f - u;
    const float u2 = u * u, u3 = u2 * u;
    const float c0 = t1 * t1 * t1 * (1.0f / 6.0f);
    const float c1 = fmaf(0.5f, u3, fmaf(-1.0f, u2, 2.0f / 3.0f));
    const float c2 = fmaf(-0.5f, u3, fmaf(0.5f, u2, fmaf(0.5f, u, 1.0f / 6.0f)));
    const float c3 = u3 * (1.0f / 6.0f);
    half8 bs = {0, 0, 0, 0, 0, 0, 0, 0};
#pragma unroll
    for (int k = 0; k < 8; ++k) {
        const int d = k - j0 + 3;              // outside weight range -> 0 (ref truncation)
        const float v = (d == 0) ? c0 : (d == 1) ? c1 : (d == 2) ? c2 : (d == 3) ? c3 : 0.0f;
        bs[k] = (half_t)v;
    }
    return bs;
}

__device__ __forceinline__ half8 cvt8(float4 a, float4 b, float s) {
    half8 r;
    r[0] = (half_t)(s * a.x); r[1] = (half_t)(s * a.y);
    r[2] = (half_t)(s * a.z); r[3] = (half_t)(s * a.w);
    r[4] = (half_t)(s * b.x); r[5] = (half_t)(s * b.y);
    r[6] = (half_t)(s * b.z); r[7] = (half_t)(s * b.w);
    return r;
}

// ---------------- D1: prep, 576 blocks (plain stores, R16-proven) ----------------
__global__ __launch_bounds__(256) void k_prep(
    const float* __restrict__ X, const float* __restrict__ G,
    const float* __restrict__ W, const float* __restrict__ Csp,
    const float* __restrict__ Cre, half_t* __restrict__ ws)
{
    const int bid = blockIdx.x, t = threadIdx.x;
    if (bid < 512) {
        // in-major: Bh2ex writes coalesced (b varies per lane); X gather read-only
        const int in = bid >> 2;
        const int b  = ((bid & 3) << 8) + t;
        const float x  = X[b * INDIM + in];
        const float g0 = G[in * 6 + 0], g5 = G[in * 6 + 5];
        *(half8*)&ws[(in * BATCH + b) * 8] = basis8(x, g0, g5);
        ws[((128 + (in >> 3)) * BATCH + b) * 8 + (in & 7)] =
            (half_t)(x / (1.0f + __expf(-x)));
    } else {
        // weights, in-major: Wc2 writes coalesced per in-row
        const int sp = (bid - 512) * 256 + t;  // in*128 + o
        const int in = sp >> 7, o = sp & 127;
        const int s  = o * INDIM + in;         // original edge index
        const float4 w0 = *(const float4*)&W[s * 8];
        const float4 w1 = *(const float4*)&W[s * 8 + 4];
        *(half8*)&ws[WC2_OFF + (in * 128 + o) * 8] = cvt8(w0, w1, Csp[s]);
        ws[WC2_OFF + ((128 + (in >> 3)) * 128 + o) * 8 + (in & 7)] = (half_t)Cre[s];
    }
}

// ---------------- D2: y (128 blocks) + REG (2048 blocks, b-split x2) ----------------
__global__ __launch_bounds__(256) void k_main(
    const float* __restrict__ G, const float* __restrict__ W,
    const half_t* __restrict__ ws,
    float* __restrict__ Y, float* __restrict__ REG)
{
    __shared__ float SH[64];                   // REG-role reduce only (256 B)
    const int bid = blockIdx.x, t = threadIdx.x;
    const int w = t >> 6, lane = t & 63;
    const int col = lane & 15, quad = lane >> 4;
    const f32x4 zero4 = {0.f, 0.f, 0.f, 0.f};

    if (bid < 128) {
        // ---- y role: 16b x 64o tile, zero LDS, zero syncthreads ----
        const int m0 = (bid >> 1) * 16;
        const int nh = bid & 1;
        const int o  = nh * 64 + w * 16 + col;
        f32x4 acc = zero4;
#pragma unroll 6
        for (int kt = 0; kt < 36; ++kt) {
            const int kc = kt * 4 + quad;
            const half8 a = *(const half8*)&ws[(kc * BATCH + m0 + col) * 8];
            const half8 b = *(const half8*)&ws[WC2_OFF + (kc * 128 + o) * 8];
            acc = __builtin_amdgcn_mfma_f32_16x16x32_f16(a, b, acc, 0, 0, 0);
        }
#pragma unroll
        for (int r = 0; r < 4; ++r)
            Y[(m0 + quad * 4 + r) * OUTDIM + o] = acc[r] * (1.0f / INDIM);
    } else {
        // ---- REG role: (in, 16-o slice, b-half); 2 blocks/output via atomicAdd ----
        const int rb = bid - 128;              // 0..2047
        const int in = rb & 127;
        const int oq = (rb >> 7) & 7;          // 16-o slice
        const int bh = rb >> 10;               // b-half (0/1)
        const int o0 = oq * 16;

        // raw W fragment, converted in-kernel; quad0-only k-map cancels on A and B
        half8 bfrag = {0, 0, 0, 0, 0, 0, 0, 0};
        if (quad == 0) {
            const int s = (o0 + col) * INDIM + in;
            const float4 w0 = *(const float4*)&W[s * 8];
            const float4 w1 = *(const float4*)&W[s * 8 + 4];
            bfrag = cvt8(w0, w1, 1.0f);
        }
        float r0 = 0.f, r1 = 0.f, r2 = 0.f, r3 = 0.f;
        const int bt0 = bh * 32 + w * 8;       // 8 consecutive b-tiles per wave
#pragma unroll 4
        for (int bt = bt0; bt < bt0 + 8; ++bt) {
            half8 a = {0, 0, 0, 0, 0, 0, 0, 0};
            if (quad == 0)
                a = *(const half8*)&ws[(in * BATCH + bt * 16 + col) * 8];  // 256B contig
            const f32x4 c = __builtin_amdgcn_mfma_f32_16x16x32_f16(a, bfrag, zero4, 0, 0, 0);
            r0 += fabsf(c[0]); r1 += fabsf(c[1]); r2 += fabsf(c[2]); r3 += fabsf(c[3]);
        }
        float sum = (r0 + r1) + (r2 + r3);
        sum += __shfl_xor(sum, 16);
        sum += __shfl_xor(sum, 32);
        if (lane < 16) SH[w * 16 + lane] = sum;
        __syncthreads();
        if (t < 16) {
            const int s = (o0 + t) * INDIM + in;
            const float gg0 = G[s * 6], gg5 = G[s * 6 + 5];
            // 2 contributors per s: fp32 add of 2 terms is order-independent
            atomicAdd(&REG[s], (SH[t] + SH[16 + t] + SH[32 + t] + SH[48 + t])
                               * (1.0f / BATCH) / (gg5 - gg0 + 1e-5f));
        }
    }
}

extern "C" void kernel_launch(void* const* d_in, const int* in_sizes, int n_in,
                              void* d_out, int out_size, void* d_ws, size_t ws_size,
                              hipStream_t stream) {
    const float* X   = (const float*)d_in[0];
    const float* G   = (const float*)d_in[1];
    const float* W   = (const float*)d_in[2];
    const float* Csp = (const float*)d_in[3];
    const float* Cre = (const float*)d_in[4];
    float* Y   = (float*)d_out;                    // (1024,128) unique-owner stores
    float* REG = (float*)d_out + BATCH * OUTDIM;   // (128,128)  atomic, 2 contributors
    half_t* ws = (half_t*)d_ws;

    // REG is accumulated via atomics — zero it (64 KB); Y fully overwritten.
    (void)hipMemsetAsync(REG, 0, (size_t)(OUTDIM * INDIM) * sizeof(float), stream);
    k_prep<<<576, 256, 0, stream>>>(X, G, W, Csp, Cre, ws);
    k_main<<<2176, 256, 0, stream>>>(G, W, ws, Y, REG);
}

// Round 20
// 18.151 us; speedup vs baseline: 1.2758x; 1.2758x over previous
//
#include <hip/hip_runtime.h>

#define INDIM  128
#define OUTDIM 128
#define GSZ    5
#define BATCH  1024
#define KC     144       // K-chunks: 128 basis (kc=in) + 16 silu chunks

typedef _Float16 half_t;
typedef _Float16 half8 __attribute__((ext_vector_type(8)));
typedef float    f32x4 __attribute__((ext_vector_type(4)));

// ws layout (half_t units), all K-chunk-major:
//  Bh2ex [144][1024][8] : [kc][b][j]  kc<128: basis_j(b, in=kc)
//                                     kc>=128: silu(b, in=(kc-128)*8+j)
//  Wc2   [144][128][8]  : [kc][o][j]  kc<128: csp*W[o,in=kc,j]
//                                     kc>=128: cre[o, in=(kc-128)*8+j]
// y-GEMM:  A-frag = Bh2ex[kc][m0+col]  (256B contig per quad-group)
//          B-frag = Wc2[kc][o]         (256B contig)
// REG:     A-frag = Bh2ex[in][bt*16+col] (basis region doubles as REG A)
#define WC2_OFF  (KC * BATCH * 8)                  // 1179648

// 8 weight-slot basis values for one x (uniform cubic B-spline, reference knots)
__device__ __forceinline__ half8 basis8(float x, float g0, float g5) {
    const float h  = (g5 - g0) * (1.0f / GSZ);
    const float e0 = ((g0 - h) - h) - h;       // matches reference sequential knot build
    const float xb = (x - e0) * (1.0f / h);
    const float jf = floorf(xb);
    const int   j0 = (int)jf;
    const float u  = xb - jf;
    const float t1 = 1.0f - u;
    const float u2 = u * u, u3 = u2 * u;
    const float c0 = t1 * t1 * t1 * (1.0f / 6.0f);
    const float c1 = fmaf(0.5f, u3, fmaf(-1.0f, u2, 2.0f / 3.0f));
    const float c2 = fmaf(-0.5f, u3, fmaf(0.5f, u2, fmaf(0.5f, u, 1.0f / 6.0f)));
    const float c3 = u3 * (1.0f / 6.0f);
    half8 bs = {0, 0, 0, 0, 0, 0, 0, 0};
#pragma unroll
    for (int k = 0; k < 8; ++k) {
        const int d = k - j0 + 3;              // outside weight range -> 0 (ref truncation)
        const float v = (d == 0) ? c0 : (d == 1) ? c1 : (d == 2) ? c2 : (d == 3) ? c3 : 0.0f;
        bs[k] = (half_t)v;
    }
    return bs;
}

__device__ __forceinline__ half8 cvt8(float4 a, float4 b, float s) {
    half8 r;
    r[0] = (half_t)(s * a.x); r[1] = (half_t)(s * a.y);
    r[2] = (half_t)(s * a.z); r[3] = (half_t)(s * a.w);
    r[4] = (half_t)(s * b.x); r[5] = (half_t)(s * b.y);
    r[6] = (half_t)(s * b.z); r[7] = (half_t)(s * b.w);
    return r;
}

// ---------------- D1: prep, 576 blocks ----------------
__global__ __launch_bounds__(256) void k_prep(
    const float* __restrict__ X, const float* __restrict__ G,
    const float* __restrict__ W, const float* __restrict__ Csp,
    const float* __restrict__ Cre, half_t* __restrict__ ws)
{
    const int bid = blockIdx.x, t = threadIdx.x;
    if (bid < 512) {
        // in-major: Bh2ex writes coalesced (b varies per lane); X gather read-only
        const int in = bid >> 2;
        const int b  = ((bid & 3) << 8) + t;
        const float x  = X[b * INDIM + in];
        const float g0 = G[in * 6 + 0], g5 = G[in * 6 + 5];
        *(half8*)&ws[(in * BATCH + b) * 8] = basis8(x, g0, g5);
        ws[((128 + (in >> 3)) * BATCH + b) * 8 + (in & 7)] =
            (half_t)(x / (1.0f + __expf(-x)));
    } else {
        // weights, in-major: Wc2 writes coalesced per in-row
        const int sp = (bid - 512) * 256 + t;  // in*128 + o
        const int in = sp >> 7, o = sp & 127;
        const int s  = o * INDIM + in;         // original edge index
        const float4 w0 = *(const float4*)&W[s * 8];
        const float4 w1 = *(const float4*)&W[s * 8 + 4];
        *(half8*)&ws[WC2_OFF + (in * 128 + o) * 8] = cvt8(w0, w1, Csp[s]);
        ws[WC2_OFF + ((128 + (in >> 3)) * 128 + o) * 8 + (in & 7)] = (half_t)Cre[s];
    }
}

// ---------------- D2: y (bid<128, LDS-free) + REG (1024 blocks, 256B LDS) ----------------
__global__ __launch_bounds__(256) void k_main(
    const float* __restrict__ G, const float* __restrict__ W,
    const half_t* __restrict__ ws,
    float* __restrict__ Y, float* __restrict__ REG)
{
    __shared__ float SH[64];                   // REG-role reduce only (256 B)
    const int bid = blockIdx.x, t = threadIdx.x;
    const int w = t >> 6, lane = t & 63;
    const int col = lane & 15, quad = lane >> 4;
    const f32x4 zero4 = {0.f, 0.f, 0.f, 0.f};

    if (bid < 128) {
        // ---- y role: 16b x 64o tile, zero LDS, zero syncthreads ----
        const int m0 = (bid >> 1) * 16;
        const int nh = bid & 1;
        const int o  = nh * 64 + w * 16 + col;
        f32x4 acc = zero4;
#pragma unroll 6
        for (int kt = 0; kt < 36; ++kt) {
            const int kc = kt * 4 + quad;
            const half8 a = *(const half8*)&ws[(kc * BATCH + m0 + col) * 8];
            const half8 b = *(const half8*)&ws[WC2_OFF + (kc * 128 + o) * 8];
            acc = __builtin_amdgcn_mfma_f32_16x16x32_f16(a, b, acc, 0, 0, 0);
        }
#pragma unroll
        for (int r = 0; r < 4; ++r)
            Y[(m0 + quad * 4 + r) * OUTDIM + o] = acc[r] * (1.0f / INDIM);
    } else {
        // ---- REG role: (in, 16-o slice), |spl| over all b ----
        const int rb = bid - 128;
        const int in = rb & 127;
        const int o0 = (rb >> 7) * 16;

        // raw W fragment, converted in-kernel; quad0-only k-map cancels on A and B
        half8 bfrag = {0, 0, 0, 0, 0, 0, 0, 0};
        if (quad == 0) {
            const int s = (o0 + col) * INDIM + in;
            const float4 w0 = *(const float4*)&W[s * 8];
            const float4 w1 = *(const float4*)&W[s * 8 + 4];
            bfrag = cvt8(w0, w1, 1.0f);
        }
        float r0 = 0.f, r1 = 0.f, r2 = 0.f, r3 = 0.f;
#pragma unroll 4
        for (int bt = w; bt < 64; bt += 4) {   // 4 waves split the 64 b-tiles
            half8 a = {0, 0, 0, 0, 0, 0, 0, 0};
            if (quad == 0)
                a = *(const half8*)&ws[(in * BATCH + bt * 16 + col) * 8];  // 256B contig
            const f32x4 c = __builtin_amdgcn_mfma_f32_16x16x32_f16(a, bfrag, zero4, 0, 0, 0);
            r0 += fabsf(c[0]); r1 += fabsf(c[1]); r2 += fabsf(c[2]); r3 += fabsf(c[3]);
        }
        float sum = (r0 + r1) + (r2 + r3);
        sum += __shfl_xor(sum, 16);
        sum += __shfl_xor(sum, 32);
        if (lane < 16) SH[w * 16 + lane] = sum;
        __syncthreads();
        if (t < 16) {
            const int s = (o0 + t) * INDIM + in;
            const float gg0 = G[s * 6], gg5 = G[s * 6 + 5];
            REG[s] = (SH[t] + SH[16 + t] + SH[32 + t] + SH[48 + t])
                     * (1.0f / BATCH) / (gg5 - gg0 + 1e-5f);
        }
    }
}

extern "C" void kernel_launch(void* const* d_in, const int* in_sizes, int n_in,
                              void* d_out, int out_size, void* d_ws, size_t ws_size,
                              hipStream_t stream) {
    const float* X   = (const float*)d_in[0];
    const float* G   = (const float*)d_in[1];
    const float* W   = (const float*)d_in[2];
    const float* Csp = (const float*)d_in[3];
    const float* Cre = (const float*)d_in[4];
    float* Y   = (float*)d_out;                    // (1024,128) unique-owner stores
    float* REG = (float*)d_out + BATCH * OUTDIM;   // (128,128)  unique-owner stores
    half_t* ws = (half_t*)d_ws;

    k_prep<<<576, 256, 0, stream>>>(X, G, W, Csp, Cre, ws);
    k_main<<<1152, 256, 0, stream>>>(G, W, ws, Y, REG);
}